// Round 16
// baseline (672.988 us; speedup 1.0000x reference)
//
#include <hip/hip_runtime.h>
#include <hip/hip_fp16.h>

#define LDIM 50
#define MBIN 262144
#define ODIM 155
#define VOCABSZ 100

typedef _Float16 f16x4 __attribute__((ext_vector_type(4)));
typedef _Float16 f16x2 __attribute__((ext_vector_type(2)));
typedef float    f32x4 __attribute__((ext_vector_type(4)));

// packed fp16 relu: v_pk_max_f16 with 0 (ROCm 7.2 header lacks __hmax2)
static __device__ __forceinline__ __half2 relu2(__half2 a) {
    f16x2 av; __builtin_memcpy(&av, &a, sizeof(av));
    const f16x2 zv = {(_Float16)0.0f, (_Float16)0.0f};
    f16x2 r = __builtin_elementwise_max(av, zv);
    __half2 out; __builtin_memcpy(&out, &r, sizeof(out));
    return out;
}

// ---- workspace half-offsets (from (__half*)ws) ----
#define H_TBL  0       // 800*56 halves padded gather tables (T|pe|ve)
#define H_TO   44800   // [100][50] half2 pairs {Tb, oe}
#define H_WC   54800   // WtCat  [64][116]  (232B rows)
#define H_WU   62224   // W_unT  [64][68]   (136B rows)
#define H_WV   66576   // W_univT[64][68]
#define H_WF   70928   // W_finT [160][68]  (ends 81808)
#define H_WATT 81808   // 28 half2 padded W_att (56 halves, ends 81864 < 81920)
#define F_LG   40960   // float-offset: 300 attention logits fp32 (halves 81920..)

// ---- LDS: per-wave 4736 B (slab 3712 + 4x64 scalars), 2 waves/block ----
#define LB_WAVE 4736
#define LDS_BYTES (2*LB_WAVE)   // 9472 B -> 8 blocks/CU = 16 waves/CU

// ---------------------------------------------------------------------------
// Precompute: round-14/15 proven + watt half2 table
// ---------------------------------------------------------------------------
__global__ __launch_bounds__(256) void precompute_kernel(
    const float* __restrict__ pe, const float* __restrict__ ve, const float* __restrict__ oe,
    const float* __restrict__ W_pred, const float* __restrict__ b_pred,
    const float* __restrict__ W_bin, const float* __restrict__ b_bin,
    const float* __restrict__ W_un, const float* __restrict__ W_univ,
    const float* __restrict__ W_fin,
    const float* __restrict__ W_att, const float* __restrict__ b_att,
    float* __restrict__ ws)
{
    __half* wsh = (__half*)ws;
    const int bid = blockIdx.x, tid = threadIdx.x;
    if (bid < 150) {
        const int row = bid*4 + (tid >> 6);
        const int t = tid & 63;
        const int s = row / VOCABSZ, v = row % VOCABSZ;
        if (t < 56) {
            float acc = 0.0f;
            if (t < 50) {
                acc = (s == 0) ? b_pred[t] : 0.0f;
                const float* E = (s == 0) ? pe : ve;
#pragma unroll
                for (int e = 0; e < 50; ++e)
                    acc += E[v*50 + e] * W_pred[(s*50 + e)*50 + t];
            }
            wsh[H_TBL + row*56 + t] = __float2half_rn(acc);
        }
    } else if (bid < 152) {
        const int which = bid - 150;
        const float* E = which ? ve : pe;
        const int base = H_TBL + (600 + which*100) * 56;
        for (int idx = tid; idx < 5600; idx += 256) {
            const int r = idx / 56, c = idx % 56;
            wsh[base + idx] = __float2half_rn((c < 50) ? E[r*50 + c] : 0.0f);
        }
    } else if (bid < 177) {
        const int v = (bid - 152)*4 + (tid >> 6);
        const int t = tid & 63;
        if (t < 50) {
            float acc = b_bin[t];
#pragma unroll
            for (int e = 0; e < 50; ++e)
                acc += oe[v*50 + e] * W_bin[(50 + e)*50 + t];
            wsh[H_TO + (v*50 + t)*2]     = __float2half_rn(acc);
            wsh[H_TO + (v*50 + t)*2 + 1] = __float2half_rn(oe[v*50 + t]);
        }
    } else if (bid == 177) {
        const int n = tid & 63, kc = tid >> 6;
        for (int k = kc*29; k < kc*29 + 29; ++k) {
            float val = 0.0f;
            if (n < 50) {
                if (k < 50)       val = W_bin[k*50 + n];
                else if (k < 100) val = W_bin[(100 + k - 50)*50 + n];
            }
            wsh[H_WC + n*116 + k] = __float2half_rn(val);
        }
    } else if (bid == 178) {
        const int n = tid & 63;
        const int half = tid >> 7;
        const int kc = (tid >> 6) & 1;
        const float* W = half ? W_univ : W_un;
        const int base = half ? H_WV : H_WU;
        for (int k = kc*34; k < kc*34 + 34; ++k) {
            float val = (n < 50 && k < 50) ? W[k*50 + n] : 0.0f;
            wsh[base + n*68 + k] = __float2half_rn(val);
        }
    } else if (bid == 179) {
        for (int idx = tid; idx < 10880; idx += 256) {
            const int n = idx % 160, k = idx / 160;
            float val = (n < ODIM && k < 50) ? W_fin[k*ODIM + n] : 0.0f;
            wsh[H_WF + n*68 + k] = __float2half_rn(val);
        }
    } else {                                // bid == 180: logits fp32 + watt half2
        for (int g = tid; g < 300; g += 256) {
            const int which = g / VOCABSZ, v = g % VOCABSZ;
            const float* E = (which == 0) ? pe : ((which == 1) ? ve : oe);
            float acc = b_att[0];
#pragma unroll
            for (int e = 0; e < 50; ++e)
                acc += E[v*50 + e] * W_att[e];
            ws[F_LG + g] = acc;
        }
        if (tid < 28) {
            const float x = (2*tid < 50)   ? W_att[2*tid]   : 0.0f;
            const float y = (2*tid+1 < 50) ? W_att[2*tid+1] : 0.0f;
            ((__half2*)(wsh + H_WATT))[tid] = __floats2half2_rn(x, y);
        }
    }
}

// ---------------------------------------------------------------------------
// Build one predicate node — packed fp16 from GLOBAL tables (r15 proven);
// wattl is lane-uniform global (s_load stream).
// ---------------------------------------------------------------------------
__device__ __forceinline__ float build_node(
    int p, const int* __restrict__ v, __half2 e02, const __half2* __restrict__ ek2,
    __half2 invs, const uint4* __restrict__ tq, const __half2* __restrict__ wattl,
    __half2* __restrict__ h2out)
{
    const __half2 z2 = __floats2half2_rn(0.0f, 0.0f);
    __half2 lacc = z2;
#pragma unroll
    for (int g = 0; g < 7; ++g) {
        uint4 ul = tq[p*7 + g];
        uint4 up = tq[(600 + p)*7 + g];
        __half2 lin[4], num[4];
#pragma unroll
        for (int k = 0; k < 4; ++k) {
            lin[k] = ((const __half2*)&ul)[k];
            num[k] = __hmul2(e02, ((const __half2*)&up)[k]);
        }
#pragma unroll
        for (int s = 0; s < 5; ++s) {
            uint4 ua = tq[((s+1)*VOCABSZ + v[s])*7 + g];
            uint4 uv = tq[(700 + v[s])*7 + g];
#pragma unroll
            for (int k = 0; k < 4; ++k) {
                lin[k] = __hadd2(lin[k], ((const __half2*)&ua)[k]);
                num[k] = __hfma2(ek2[s], ((const __half2*)&uv)[k], num[k]);
            }
        }
#pragma unroll
        for (int k = 0; k < 4; ++k) {
            const __half2 h = __hfma2(num[k], invs, relu2(lin[k]));
            h2out[g*4 + k] = h;
            lacc = __hfma2(h, wattl[g*4 + k], lacc);
        }
    }
    return __low2float(lacc) + __high2float(lacc);
}

// ---------------------------------------------------------------------------
// Fused kernel v3: 128-thr (2-wave) blocks, ZERO barriers, each wave fully
// self-contained on a private 4.7KB LDS slab. All weights/biases/logits read
// from global L2 (shared across 4096 waves -> L2-hot). 8 blocks/CU x 2 waves
// = 16 waves/CU (vs 8 at 512-thr: rounds 4/8/10/15 proved big-block
// co-residency never happens; small blocks are the remaining residency shape).
// ---------------------------------------------------------------------------
__global__ __launch_bounds__(128, 4)
void fused_kernel(
    const float* __restrict__ b_att,
    const float* __restrict__ b_un, const float* __restrict__ b_univ,
    const float* __restrict__ b_fin,
    const int* __restrict__ pred_ids, const int* __restrict__ var_ids,
    const int* __restrict__ op_ids,
    const float* __restrict__ ws, float* __restrict__ out)
{
    __shared__ __align__(16) char ldsraw[LDS_BYTES];
    const __half* wsh = (const __half*)ws;
    const int tid = threadIdx.x;
    const int w = tid >> 6, l = tid & 63;
    const int lr = l & 15, q = l >> 4;
    const int jwb = blockIdx.x*128 + w*64;      // this wave's node base
    const int j = jwb + l;

    char* wbase = ldsraw + w*LB_WAVE;
    char* slab  = wbase;                        // [16][232B]
    int*   opw = (int*)(wbase + 3712);
    float* w0w = (float*)(wbase + 3968);
    float* w2w = (float*)(wbase + 4224);
    float* w1w = (float*)(wbase + 4480);

    const float* lgf = ws + F_LG;               // global, L2-hot
    const float batt = b_att[0];

    // ---- P1: packed-fp16 gather-build from global tables ----
    int vA[5], vB[5];
    const int pA = pred_ids[2*j], pB = pred_ids[2*j+1];
#pragma unroll
    for (int s = 0; s < 5; ++s) { vA[s] = var_ids[(2*j)*5 + s]; vB[s] = var_ids[(2*j+1)*5 + s]; }
    const int op = op_ids[j];

    float ekA[5], ekB[5];
    const float e0A = __expf(lgf[pA]);
    const float e0B = __expf(lgf[pB]);
    float denA = e0A, denB = e0B;
#pragma unroll
    for (int s = 0; s < 5; ++s) {
        ekA[s] = __expf(lgf[VOCABSZ + vA[s]]); denA += ekA[s];
        ekB[s] = __expf(lgf[VOCABSZ + vB[s]]); denB += ekB[s];
    }
    const float invA = 1.0f / denA, invB = 1.0f / denB;

    __half2 ek2A[5], ek2B[5];
#pragma unroll
    for (int s = 0; s < 5; ++s) {
        ek2A[s] = __float2half2_rn(ekA[s]);
        ek2B[s] = __float2half2_rn(ekB[s]);
    }

    const uint4* tq = (const uint4*)wsh;
    const __half2* wattg = (const __half2*)(wsh + H_WATT);   // lane-uniform

    __half2 hA2[28], hB2[28];
    const float w0 = __expf(batt + build_node(pA, vA, __float2half2_rn(e0A), ek2A,
                                              __float2half2_rn(invA), tq, wattg, hA2));
    const float w2 = __expf(batt + build_node(pB, vB, __float2half2_rn(e0B), ek2B,
                                              __float2half2_rn(invB), tq, wattg, hB2));
    const float w1 = __expf(lgf[2*VOCABSZ + op]);
    const float inv2 = 1.0f / (w0 + w1 + w2);

    // publish per-node scalars (own wave only -> wave-synchronous, no barrier)
    opw[l] = op;
    w0w[l] = w0*inv2; w2w[l] = w2*inv2; w1w[l] = w1*inv2;

    const __half2* TOg = (const __half2*)(wsh + H_TO);
    const char* Wcg = (const char*)(wsh + H_WC);    // 232B rows, global L2
    const char* Wug = (const char*)(wsh + H_WU);    // 136B rows
    const char* Wvg = (const char*)(wsh + H_WV);
    const char* Wfg = (const char*)(wsh + H_WF);

    for (int c = 0; c < 4; ++c) {
        // ---- owner lanes write chunk H rows [hA|hB|zeros] ----
        if ((l >> 4) == c) {
            uint* dst = (uint*)(slab + (l & 15)*232);
#pragma unroll
            for (int i = 0; i < 25; ++i) { uint u; __builtin_memcpy(&u, &hA2[i], 4); dst[i] = u; }
#pragma unroll
            for (int i = 0; i < 25; ++i) { uint u; __builtin_memcpy(&u, &hB2[i], 4); dst[25+i] = u; }
#pragma unroll
            for (int i = 50; i < 58; ++i) dst[i] = 0u;
        }

        // ---- GEMM1: lin2[16x64] = H[16x116(100)] @ Wcat (B from global) ----
        f32x4 C1[4];
#pragma unroll
        for (int nt = 0; nt < 4; ++nt) C1[nt] = (f32x4){0.f, 0.f, 0.f, 0.f};
#pragma unroll
        for (int kk = 0; kk < 7; ++kk) {
            f16x4 a = *(const f16x4*)(slab + lr*232 + kk*32 + q*8);
#pragma unroll
            for (int nt = 0; nt < 4; ++nt) {
                f16x4 b = *(const f16x4*)(Wcg + (nt*16 + lr)*232 + kk*32 + q*8);
                C1[nt] = __builtin_amdgcn_mfma_f32_16x16x16f16(a, b, C1[nt], 0, 0, 0);
            }
        }
        // epilogue: h_bin = relu(lin2 + Tb[op]) + w0i*hA + w2i*hB + w1i*oe[op]
        {
            const __half* sh = (const __half*)slab;
            const int cb = c*16;
#pragma unroll
            for (int nt = 0; nt < 4; ++nt) {
                const int d = nt*16 + lr;
#pragma unroll
                for (int r = 0; r < 4; ++r) {
                    float v = 0.0f;
                    if (d < LDIM) {
                        const int nw = cb + q*4 + r;
                        const int opn = opw[nw];
                        const float2 to = __half22float2(TOg[opn*LDIM + d]);   // {Tb, oe}
                        const float hAv = __half2float(sh[(q*4 + r)*116 + d]);
                        const float hBv = __half2float(sh[(q*4 + r)*116 + 50 + d]);
                        v = fmaxf(C1[nt][r] + to.x, 0.0f)
                          + w0w[nw]*hAv + w2w[nw]*hBv + w1w[nw]*to.y;
                    }
                    C1[nt][r] = v;
                }
            }
            __half* shw = (__half*)slab;
#pragma unroll
            for (int nt = 0; nt < 4; ++nt)
#pragma unroll
                for (int r = 0; r < 4; ++r)
                    shw[(q*4 + r)*116 + nt*16 + lr] = __float2half(C1[nt][r]);
        }

        // ---- GEMM2: h_un = relu(h_bin @ W_un + b_un) ----
        {
            f32x4 C2[4];
#pragma unroll
            for (int nt = 0; nt < 4; ++nt) C2[nt] = (f32x4){0.f, 0.f, 0.f, 0.f};
#pragma unroll
            for (int kk = 0; kk < 4; ++kk) {
                f16x4 a = *(const f16x4*)(slab + lr*232 + kk*32 + q*8);
#pragma unroll
                for (int nt = 0; nt < 4; ++nt) {
                    f16x4 b = *(const f16x4*)(Wug + (nt*16 + lr)*136 + kk*32 + q*8);
                    C2[nt] = __builtin_amdgcn_mfma_f32_16x16x16f16(a, b, C2[nt], 0, 0, 0);
                }
            }
            __half* shw = (__half*)slab;
#pragma unroll
            for (int nt = 0; nt < 4; ++nt) {
                const int d = nt*16 + lr;
                const float bu = (d < LDIM) ? b_un[d] : 0.0f;
#pragma unroll
                for (int r = 0; r < 4; ++r) {
                    const float v = (d < LDIM) ? fmaxf(C2[nt][r] + bu, 0.0f) : 0.0f;
                    shw[(q*4 + r)*116 + d] = __float2half(v);
                }
            }
        }

        // ---- GEMM3: h_q = relu(h_un @ W_univ + b_univ) ----
        {
            f32x4 C3[4];
#pragma unroll
            for (int nt = 0; nt < 4; ++nt) C3[nt] = (f32x4){0.f, 0.f, 0.f, 0.f};
#pragma unroll
            for (int kk = 0; kk < 4; ++kk) {
                f16x4 a = *(const f16x4*)(slab + lr*232 + kk*32 + q*8);
#pragma unroll
                for (int nt = 0; nt < 4; ++nt) {
                    f16x4 b = *(const f16x4*)(Wvg + (nt*16 + lr)*136 + kk*32 + q*8);
                    C3[nt] = __builtin_amdgcn_mfma_f32_16x16x16f16(a, b, C3[nt], 0, 0, 0);
                }
            }
            __half* shw = (__half*)slab;
#pragma unroll
            for (int nt = 0; nt < 4; ++nt) {
                const int d = nt*16 + lr;
                const float bv = (d < LDIM) ? b_univ[d] : 0.0f;
#pragma unroll
                for (int r = 0; r < 4; ++r) {
                    const float v = (d < LDIM) ? fmaxf(C3[nt][r] + bv, 0.0f) : 0.0f;
                    shw[(q*4 + r)*116 + d] = __float2half(v);
                }
            }
        }

        // ---- GEMM4: out = h_q @ W_fin + b_fin (B from global L2) ----
        {
            float* gb = out + (size_t)(jwb + c*16) * ODIM;
            for (int nt = 0; nt < 10; ++nt) {
                f16x4 bf[4];
#pragma unroll
                for (int kk = 0; kk < 4; ++kk)
                    bf[kk] = *(const f16x4*)(Wfg + (nt*16 + lr)*136 + kk*32 + q*8);
                f32x4 c4 = (f32x4){0.f, 0.f, 0.f, 0.f};
#pragma unroll
                for (int kk = 0; kk < 4; ++kk) {
                    f16x4 a = *(const f16x4*)(slab + lr*232 + kk*32 + q*8);
                    c4 = __builtin_amdgcn_mfma_f32_16x16x16f16(a, bf[kk], c4, 0, 0, 0);
                }
                const int o = nt*16 + lr;
                const float bv = (o < ODIM) ? b_fin[o] : 0.0f;
#pragma unroll
                for (int r = 0; r < 4; ++r)
                    *(float*)(slab + (q*4 + r)*232 + 128 + lr*4) = c4[r] + bv;
#pragma unroll
                for (int it = 0; it < 4; ++it) {
                    const int row = it*4 + q;
                    if (o < ODIM)
                        gb[row*ODIM + nt*16 + lr] =
                            *(const float*)(slab + row*232 + 128 + lr*4);
                }
            }
        }
    }
}

// ---------------------------------------------------------------------------
extern "C" void kernel_launch(void* const* d_in, const int* in_sizes, int n_in,
                              void* d_out, int out_size, void* d_ws, size_t ws_size,
                              hipStream_t stream) {
    const float* pe     = (const float*)d_in[0];
    const float* ve     = (const float*)d_in[1];
    const float* oe     = (const float*)d_in[2];
    const float* W_pred = (const float*)d_in[3];
    const float* b_pred = (const float*)d_in[4];
    const float* W_bin  = (const float*)d_in[5];
    const float* b_bin  = (const float*)d_in[6];
    const float* W_un   = (const float*)d_in[7];
    const float* b_un   = (const float*)d_in[8];
    const float* W_univ = (const float*)d_in[9];
    const float* b_univ = (const float*)d_in[10];
    const float* W_att  = (const float*)d_in[11];
    const float* b_att  = (const float*)d_in[12];
    const float* W_fin  = (const float*)d_in[13];
    const float* b_fin  = (const float*)d_in[14];
    const int* pred_ids = (const int*)d_in[15];
    const int* var_ids  = (const int*)d_in[16];
    const int* op_ids   = (const int*)d_in[17];
    float* out = (float*)d_out;
    float* ws  = (float*)d_ws;

    precompute_kernel<<<181, 256, 0, stream>>>(pe, ve, oe, W_pred, b_pred,
                                               W_bin, b_bin, W_un, W_univ, W_fin,
                                               W_att, b_att, ws);
    fused_kernel<<<MBIN/128, 128, 0, stream>>>(b_att, b_un, b_univ, b_fin,
                                               pred_ids, var_ids, op_ids, ws, out);
}

// Round 17
// 616.030 us; speedup vs baseline: 1.0925x; 1.0925x over previous
//
#include <hip/hip_runtime.h>
#include <hip/hip_fp16.h>

#define LDIM 50
#define MBIN 262144
#define ODIM 155
#define VOCABSZ 100

typedef _Float16 f16x4 __attribute__((ext_vector_type(4)));
typedef _Float16 f16x2 __attribute__((ext_vector_type(2)));
typedef float    f32x4 __attribute__((ext_vector_type(4)));

// packed fp16 relu: v_pk_max_f16 with 0 (ROCm 7.2 header lacks __hmax2)
static __device__ __forceinline__ __half2 relu2(__half2 a) {
    f16x2 av; __builtin_memcpy(&av, &a, sizeof(av));
    const f16x2 zv = {(_Float16)0.0f, (_Float16)0.0f};
    f16x2 r = __builtin_elementwise_max(av, zv);
    __half2 out; __builtin_memcpy(&out, &r, sizeof(out));
    return out;
}

// ---- workspace half-offsets (from (__half*)ws) ----
#define H_TBL  0       // 800*56 halves padded gather tables (T|pe|ve)
#define H_TO   44800   // [100][50] half2 pairs {Tb, oe}
#define H_WC   54800   // WtCat  [64][116]  (232B rows)
#define H_WU   62224   // W_unT  [64][68]   (136B rows)
#define H_WV   66576   // W_univT[64][68]
#define H_WF   70928   // W_finT [160][68]  (ends 81808)
#define H_WATT 81808   // 28 half2 padded W_att (56 halves, ends 81864 < 81920)
#define F_LG   40960   // float-offset: 300 attention logits fp32 (halves 81920..)

// ---- LDS: per-wave 4736 B (slab 3712 + 4x64 scalars), 2 waves/block ----
#define LB_WAVE 4736
#define LDS_BYTES (2*LB_WAVE)   // 9472 B -> 8 blocks/CU = 16 waves/CU

// ---------------------------------------------------------------------------
// Precompute: round-14/15 proven + watt half2 table
// ---------------------------------------------------------------------------
__global__ __launch_bounds__(256) void precompute_kernel(
    const float* __restrict__ pe, const float* __restrict__ ve, const float* __restrict__ oe,
    const float* __restrict__ W_pred, const float* __restrict__ b_pred,
    const float* __restrict__ W_bin, const float* __restrict__ b_bin,
    const float* __restrict__ W_un, const float* __restrict__ W_univ,
    const float* __restrict__ W_fin,
    const float* __restrict__ W_att, const float* __restrict__ b_att,
    float* __restrict__ ws)
{
    __half* wsh = (__half*)ws;
    const int bid = blockIdx.x, tid = threadIdx.x;
    if (bid < 150) {
        const int row = bid*4 + (tid >> 6);
        const int t = tid & 63;
        const int s = row / VOCABSZ, v = row % VOCABSZ;
        if (t < 56) {
            float acc = 0.0f;
            if (t < 50) {
                acc = (s == 0) ? b_pred[t] : 0.0f;
                const float* E = (s == 0) ? pe : ve;
#pragma unroll
                for (int e = 0; e < 50; ++e)
                    acc += E[v*50 + e] * W_pred[(s*50 + e)*50 + t];
            }
            wsh[H_TBL + row*56 + t] = __float2half_rn(acc);
        }
    } else if (bid < 152) {
        const int which = bid - 150;
        const float* E = which ? ve : pe;
        const int base = H_TBL + (600 + which*100) * 56;
        for (int idx = tid; idx < 5600; idx += 256) {
            const int r = idx / 56, c = idx % 56;
            wsh[base + idx] = __float2half_rn((c < 50) ? E[r*50 + c] : 0.0f);
        }
    } else if (bid < 177) {
        const int v = (bid - 152)*4 + (tid >> 6);
        const int t = tid & 63;
        if (t < 50) {
            float acc = b_bin[t];
#pragma unroll
            for (int e = 0; e < 50; ++e)
                acc += oe[v*50 + e] * W_bin[(50 + e)*50 + t];
            wsh[H_TO + (v*50 + t)*2]     = __float2half_rn(acc);
            wsh[H_TO + (v*50 + t)*2 + 1] = __float2half_rn(oe[v*50 + t]);
        }
    } else if (bid == 177) {
        const int n = tid & 63, kc = tid >> 6;
        for (int k = kc*29; k < kc*29 + 29; ++k) {
            float val = 0.0f;
            if (n < 50) {
                if (k < 50)       val = W_bin[k*50 + n];
                else if (k < 100) val = W_bin[(100 + k - 50)*50 + n];
            }
            wsh[H_WC + n*116 + k] = __float2half_rn(val);
        }
    } else if (bid == 178) {
        const int n = tid & 63;
        const int half = tid >> 7;
        const int kc = (tid >> 6) & 1;
        const float* W = half ? W_univ : W_un;
        const int base = half ? H_WV : H_WU;
        for (int k = kc*34; k < kc*34 + 34; ++k) {
            float val = (n < 50 && k < 50) ? W[k*50 + n] : 0.0f;
            wsh[base + n*68 + k] = __float2half_rn(val);
        }
    } else if (bid == 179) {
        for (int idx = tid; idx < 10880; idx += 256) {
            const int n = idx % 160, k = idx / 160;
            float val = (n < ODIM && k < 50) ? W_fin[k*ODIM + n] : 0.0f;
            wsh[H_WF + n*68 + k] = __float2half_rn(val);
        }
    } else {                                // bid == 180: logits fp32 + watt half2
        for (int g = tid; g < 300; g += 256) {
            const int which = g / VOCABSZ, v = g % VOCABSZ;
            const float* E = (which == 0) ? pe : ((which == 1) ? ve : oe);
            float acc = b_att[0];
#pragma unroll
            for (int e = 0; e < 50; ++e)
                acc += E[v*50 + e] * W_att[e];
            ws[F_LG + g] = acc;
        }
        if (tid < 28) {
            const float x = (2*tid < 50)   ? W_att[2*tid]   : 0.0f;
            const float y = (2*tid+1 < 50) ? W_att[2*tid+1] : 0.0f;
            ((__half2*)(wsh + H_WATT))[tid] = __floats2half2_rn(x, y);
        }
    }
}

// ---------------------------------------------------------------------------
// Build one predicate node — packed fp16 from GLOBAL tables (r15 proven)
// ---------------------------------------------------------------------------
__device__ __forceinline__ float build_node(
    int p, const int* __restrict__ v, __half2 e02, const __half2* __restrict__ ek2,
    __half2 invs, const uint4* __restrict__ tq, const __half2* __restrict__ wattl,
    __half2* __restrict__ h2out)
{
    const __half2 z2 = __floats2half2_rn(0.0f, 0.0f);
    __half2 lacc = z2;
#pragma unroll
    for (int g = 0; g < 7; ++g) {
        uint4 ul = tq[p*7 + g];
        uint4 up = tq[(600 + p)*7 + g];
        __half2 lin[4], num[4];
#pragma unroll
        for (int k = 0; k < 4; ++k) {
            lin[k] = ((const __half2*)&ul)[k];
            num[k] = __hmul2(e02, ((const __half2*)&up)[k]);
        }
#pragma unroll
        for (int s = 0; s < 5; ++s) {
            uint4 ua = tq[((s+1)*VOCABSZ + v[s])*7 + g];
            uint4 uv = tq[(700 + v[s])*7 + g];
#pragma unroll
            for (int k = 0; k < 4; ++k) {
                lin[k] = __hadd2(lin[k], ((const __half2*)&ua)[k]);
                num[k] = __hfma2(ek2[s], ((const __half2*)&uv)[k], num[k]);
            }
        }
#pragma unroll
        for (int k = 0; k < 4; ++k) {
            const __half2 h = __hfma2(num[k], invs, relu2(lin[k]));
            h2out[g*4 + k] = h;
            lacc = __hfma2(h, wattl[g*4 + k], lacc);
        }
    }
    return __low2float(lacc) + __high2float(lacc);
}

// ---------------------------------------------------------------------------
// Fused kernel v3.1: 128-thr (2-wave) blocks, zero barriers (r16 structure —
// occupancy 42% PROVEN) + amdgpu_waves_per_eu(4,4) to PIN the register
// allocator at the 128-VGPR budget (r16 lesson: free allocator chose 64 and
// spilled the 56-reg h-state -> 1.1GB scratch traffic; max-waves=4 removes
// its incentive to shrink below 512/4=128).
// ---------------------------------------------------------------------------
__global__ __launch_bounds__(128) __attribute__((amdgpu_waves_per_eu(4, 4)))
void fused_kernel(
    const float* __restrict__ b_att,
    const float* __restrict__ b_un, const float* __restrict__ b_univ,
    const float* __restrict__ b_fin,
    const int* __restrict__ pred_ids, const int* __restrict__ var_ids,
    const int* __restrict__ op_ids,
    const float* __restrict__ ws, float* __restrict__ out)
{
    __shared__ __align__(16) char ldsraw[LDS_BYTES];
    const __half* wsh = (const __half*)ws;
    const int tid = threadIdx.x;
    const int w = tid >> 6, l = tid & 63;
    const int lr = l & 15, q = l >> 4;
    const int jwb = blockIdx.x*128 + w*64;      // this wave's node base
    const int j = jwb + l;

    char* wbase = ldsraw + w*LB_WAVE;
    char* slab  = wbase;                        // [16][232B]
    int*   opw = (int*)(wbase + 3712);
    float* w0w = (float*)(wbase + 3968);
    float* w2w = (float*)(wbase + 4224);
    float* w1w = (float*)(wbase + 4480);

    const float* lgf = ws + F_LG;               // global, L2-hot
    const float batt = b_att[0];

    // ---- P1: packed-fp16 gather-build from global tables ----
    int vA[5], vB[5];
    const int pA = pred_ids[2*j], pB = pred_ids[2*j+1];
#pragma unroll
    for (int s = 0; s < 5; ++s) { vA[s] = var_ids[(2*j)*5 + s]; vB[s] = var_ids[(2*j+1)*5 + s]; }
    const int op = op_ids[j];

    float ekA[5], ekB[5];
    const float e0A = __expf(lgf[pA]);
    const float e0B = __expf(lgf[pB]);
    float denA = e0A, denB = e0B;
#pragma unroll
    for (int s = 0; s < 5; ++s) {
        ekA[s] = __expf(lgf[VOCABSZ + vA[s]]); denA += ekA[s];
        ekB[s] = __expf(lgf[VOCABSZ + vB[s]]); denB += ekB[s];
    }
    const float invA = 1.0f / denA, invB = 1.0f / denB;

    __half2 ek2A[5], ek2B[5];
#pragma unroll
    for (int s = 0; s < 5; ++s) {
        ek2A[s] = __float2half2_rn(ekA[s]);
        ek2B[s] = __float2half2_rn(ekB[s]);
    }

    const uint4* tq = (const uint4*)wsh;
    const __half2* wattg = (const __half2*)(wsh + H_WATT);   // lane-uniform

    __half2 hA2[28], hB2[28];
    const float w0 = __expf(batt + build_node(pA, vA, __float2half2_rn(e0A), ek2A,
                                              __float2half2_rn(invA), tq, wattg, hA2));
    const float w2 = __expf(batt + build_node(pB, vB, __float2half2_rn(e0B), ek2B,
                                              __float2half2_rn(invB), tq, wattg, hB2));
    const float w1 = __expf(lgf[2*VOCABSZ + op]);
    const float inv2 = 1.0f / (w0 + w1 + w2);

    // publish per-node scalars (own wave only -> wave-synchronous, no barrier)
    opw[l] = op;
    w0w[l] = w0*inv2; w2w[l] = w2*inv2; w1w[l] = w1*inv2;

    const __half2* TOg = (const __half2*)(wsh + H_TO);
    const char* Wcg = (const char*)(wsh + H_WC);    // 232B rows, global L2
    const char* Wug = (const char*)(wsh + H_WU);    // 136B rows
    const char* Wvg = (const char*)(wsh + H_WV);
    const char* Wfg = (const char*)(wsh + H_WF);

    for (int c = 0; c < 4; ++c) {
        // ---- owner lanes write chunk H rows [hA|hB|zeros] ----
        if ((l >> 4) == c) {
            uint* dst = (uint*)(slab + (l & 15)*232);
#pragma unroll
            for (int i = 0; i < 25; ++i) { uint u; __builtin_memcpy(&u, &hA2[i], 4); dst[i] = u; }
#pragma unroll
            for (int i = 0; i < 25; ++i) { uint u; __builtin_memcpy(&u, &hB2[i], 4); dst[25+i] = u; }
#pragma unroll
            for (int i = 50; i < 58; ++i) dst[i] = 0u;
        }

        // ---- GEMM1: lin2[16x64] = H[16x116(100)] @ Wcat (B from global) ----
        f32x4 C1[4];
#pragma unroll
        for (int nt = 0; nt < 4; ++nt) C1[nt] = (f32x4){0.f, 0.f, 0.f, 0.f};
#pragma unroll
        for (int kk = 0; kk < 7; ++kk) {
            f16x4 a = *(const f16x4*)(slab + lr*232 + kk*32 + q*8);
#pragma unroll
            for (int nt = 0; nt < 4; ++nt) {
                f16x4 b = *(const f16x4*)(Wcg + (nt*16 + lr)*232 + kk*32 + q*8);
                C1[nt] = __builtin_amdgcn_mfma_f32_16x16x16f16(a, b, C1[nt], 0, 0, 0);
            }
        }
        // epilogue: h_bin = relu(lin2 + Tb[op]) + w0i*hA + w2i*hB + w1i*oe[op]
        {
            const __half* sh = (const __half*)slab;
            const int cb = c*16;
#pragma unroll
            for (int nt = 0; nt < 4; ++nt) {
                const int d = nt*16 + lr;
#pragma unroll
                for (int r = 0; r < 4; ++r) {
                    float v = 0.0f;
                    if (d < LDIM) {
                        const int nw = cb + q*4 + r;
                        const int opn = opw[nw];
                        const float2 to = __half22float2(TOg[opn*LDIM + d]);   // {Tb, oe}
                        const float hAv = __half2float(sh[(q*4 + r)*116 + d]);
                        const float hBv = __half2float(sh[(q*4 + r)*116 + 50 + d]);
                        v = fmaxf(C1[nt][r] + to.x, 0.0f)
                          + w0w[nw]*hAv + w2w[nw]*hBv + w1w[nw]*to.y;
                    }
                    C1[nt][r] = v;
                }
            }
            __half* shw = (__half*)slab;
#pragma unroll
            for (int nt = 0; nt < 4; ++nt)
#pragma unroll
                for (int r = 0; r < 4; ++r)
                    shw[(q*4 + r)*116 + nt*16 + lr] = __float2half(C1[nt][r]);
        }

        // ---- GEMM2: h_un = relu(h_bin @ W_un + b_un) ----
        {
            f32x4 C2[4];
#pragma unroll
            for (int nt = 0; nt < 4; ++nt) C2[nt] = (f32x4){0.f, 0.f, 0.f, 0.f};
#pragma unroll
            for (int kk = 0; kk < 4; ++kk) {
                f16x4 a = *(const f16x4*)(slab + lr*232 + kk*32 + q*8);
#pragma unroll
                for (int nt = 0; nt < 4; ++nt) {
                    f16x4 b = *(const f16x4*)(Wug + (nt*16 + lr)*136 + kk*32 + q*8);
                    C2[nt] = __builtin_amdgcn_mfma_f32_16x16x16f16(a, b, C2[nt], 0, 0, 0);
                }
            }
            __half* shw = (__half*)slab;
#pragma unroll
            for (int nt = 0; nt < 4; ++nt) {
                const int d = nt*16 + lr;
                const float bu = (d < LDIM) ? b_un[d] : 0.0f;
#pragma unroll
                for (int r = 0; r < 4; ++r) {
                    const float v = (d < LDIM) ? fmaxf(C2[nt][r] + bu, 0.0f) : 0.0f;
                    shw[(q*4 + r)*116 + d] = __float2half(v);
                }
            }
        }

        // ---- GEMM3: h_q = relu(h_un @ W_univ + b_univ) ----
        {
            f32x4 C3[4];
#pragma unroll
            for (int nt = 0; nt < 4; ++nt) C3[nt] = (f32x4){0.f, 0.f, 0.f, 0.f};
#pragma unroll
            for (int kk = 0; kk < 4; ++kk) {
                f16x4 a = *(const f16x4*)(slab + lr*232 + kk*32 + q*8);
#pragma unroll
                for (int nt = 0; nt < 4; ++nt) {
                    f16x4 b = *(const f16x4*)(Wvg + (nt*16 + lr)*136 + kk*32 + q*8);
                    C3[nt] = __builtin_amdgcn_mfma_f32_16x16x16f16(a, b, C3[nt], 0, 0, 0);
                }
            }
            __half* shw = (__half*)slab;
#pragma unroll
            for (int nt = 0; nt < 4; ++nt) {
                const int d = nt*16 + lr;
                const float bv = (d < LDIM) ? b_univ[d] : 0.0f;
#pragma unroll
                for (int r = 0; r < 4; ++r) {
                    const float v = (d < LDIM) ? fmaxf(C3[nt][r] + bv, 0.0f) : 0.0f;
                    shw[(q*4 + r)*116 + d] = __float2half(v);
                }
            }
        }

        // ---- GEMM4: out = h_q @ W_fin + b_fin (B from global L2) ----
        {
            float* gb = out + (size_t)(jwb + c*16) * ODIM;
            for (int nt = 0; nt < 10; ++nt) {
                f16x4 bf[4];
#pragma unroll
                for (int kk = 0; kk < 4; ++kk)
                    bf[kk] = *(const f16x4*)(Wfg + (nt*16 + lr)*136 + kk*32 + q*8);
                f32x4 c4 = (f32x4){0.f, 0.f, 0.f, 0.f};
#pragma unroll
                for (int kk = 0; kk < 4; ++kk) {
                    f16x4 a = *(const f16x4*)(slab + lr*232 + kk*32 + q*8);
                    c4 = __builtin_amdgcn_mfma_f32_16x16x16f16(a, bf[kk], c4, 0, 0, 0);
                }
                const int o = nt*16 + lr;
                const float bv = (o < ODIM) ? b_fin[o] : 0.0f;
#pragma unroll
                for (int r = 0; r < 4; ++r)
                    *(float*)(slab + (q*4 + r)*232 + 128 + lr*4) = c4[r] + bv;
#pragma unroll
                for (int it = 0; it < 4; ++it) {
                    const int row = it*4 + q;
                    if (o < ODIM)
                        gb[row*ODIM + nt*16 + lr] =
                            *(const float*)(slab + row*232 + 128 + lr*4);
                }
            }
        }
    }
}

// ---------------------------------------------------------------------------
extern "C" void kernel_launch(void* const* d_in, const int* in_sizes, int n_in,
                              void* d_out, int out_size, void* d_ws, size_t ws_size,
                              hipStream_t stream) {
    const float* pe     = (const float*)d_in[0];
    const float* ve     = (const float*)d_in[1];
    const float* oe     = (const float*)d_in[2];
    const float* W_pred = (const float*)d_in[3];
    const float* b_pred = (const float*)d_in[4];
    const float* W_bin  = (const float*)d_in[5];
    const float* b_bin  = (const float*)d_in[6];
    const float* W_un   = (const float*)d_in[7];
    const float* b_un   = (const float*)d_in[8];
    const float* W_univ = (const float*)d_in[9];
    const float* b_univ = (const float*)d_in[10];
    const float* W_att  = (const float*)d_in[11];
    const float* b_att  = (const float*)d_in[12];
    const float* W_fin  = (const float*)d_in[13];
    const float* b_fin  = (const float*)d_in[14];
    const int* pred_ids = (const int*)d_in[15];
    const int* var_ids  = (const int*)d_in[16];
    const int* op_ids   = (const int*)d_in[17];
    float* out = (float*)d_out;
    float* ws  = (float*)d_ws;

    precompute_kernel<<<181, 256, 0, stream>>>(pe, ve, oe, W_pred, b_pred,
                                               W_bin, b_bin, W_un, W_univ, W_fin,
                                               W_att, b_att, ws);
    fused_kernel<<<MBIN/128, 128, 0, stream>>>(b_att, b_un, b_univ, b_fin,
                                               pred_ids, var_ids, op_ids, ws, out);
}

// Round 18
// 351.733 us; speedup vs baseline: 1.9133x; 1.7514x over previous
//
#include <hip/hip_runtime.h>
#include <hip/hip_fp16.h>

#define LDIM 50
#define MBIN 262144
#define ODIM 155
#define VOCABSZ 100

typedef _Float16 f16x4 __attribute__((ext_vector_type(4)));
typedef _Float16 f16x2 __attribute__((ext_vector_type(2)));
typedef float    f32x4 __attribute__((ext_vector_type(4)));

// packed fp16 relu: v_pk_max_f16 with 0 (ROCm 7.2 header lacks __hmax2)
static __device__ __forceinline__ __half2 relu2(__half2 a) {
    f16x2 av; __builtin_memcpy(&av, &a, sizeof(av));
    const f16x2 zv = {(_Float16)0.0f, (_Float16)0.0f};
    f16x2 r = __builtin_elementwise_max(av, zv);
    __half2 out; __builtin_memcpy(&out, &r, sizeof(out));
    return out;
}

// ---- workspace half-offsets (from (__half*)ws) ----
#define H_TBL  0       // 800*56 halves padded gather tables (T|pe|ve)
#define H_TO   44800   // [100][50] half2 pairs {Tb, oe}
#define H_WC   54800   // WtCat  [64][116]  (232B rows)
#define H_WU   62224   // W_unT  [64][68]   (136B rows)
#define H_WV   66576   // W_univT[64][68]
#define H_WF   70928   // W_finT [160][68]  (ends 81808)
#define H_WATT 81808   // 28 half2 padded W_att (56 halves, ends 81864 < 81920)
#define F_LG   40960   // float-offset: 300 attention logits fp32 (halves 81920..)

// ---- LDS: per-wave 4736 B (slab 3712 + 4x64 scalars), 4 waves/block.
// DECLARED size padded to 36864 B: floor(163840/36864)=4 WGs/CU -> 16 waves/CU
// -> 4 waves/EU -> the allocator's own occupancy model yields a 512/4 = 128
// VGPR budget (r0/r4/r15 precedent: big-LDS 512-thr always got 128; r16/r17:
// small-LDS always got 64 + spills. Attributes are ignored; LDS size is the
// only lever that steers the allocator.)
#define LB_WAVE 4736
#define LDS_BYTES 36864

// ---------------------------------------------------------------------------
// Precompute: round-14/15 proven + watt half2 table
// ---------------------------------------------------------------------------
__global__ __launch_bounds__(256) void precompute_kernel(
    const float* __restrict__ pe, const float* __restrict__ ve, const float* __restrict__ oe,
    const float* __restrict__ W_pred, const float* __restrict__ b_pred,
    const float* __restrict__ W_bin, const float* __restrict__ b_bin,
    const float* __restrict__ W_un, const float* __restrict__ W_univ,
    const float* __restrict__ W_fin,
    const float* __restrict__ W_att, const float* __restrict__ b_att,
    float* __restrict__ ws)
{
    __half* wsh = (__half*)ws;
    const int bid = blockIdx.x, tid = threadIdx.x;
    if (bid < 150) {
        const int row = bid*4 + (tid >> 6);
        const int t = tid & 63;
        const int s = row / VOCABSZ, v = row % VOCABSZ;
        if (t < 56) {
            float acc = 0.0f;
            if (t < 50) {
                acc = (s == 0) ? b_pred[t] : 0.0f;
                const float* E = (s == 0) ? pe : ve;
#pragma unroll
                for (int e = 0; e < 50; ++e)
                    acc += E[v*50 + e] * W_pred[(s*50 + e)*50 + t];
            }
            wsh[H_TBL + row*56 + t] = __float2half_rn(acc);
        }
    } else if (bid < 152) {
        const int which = bid - 150;
        const float* E = which ? ve : pe;
        const int base = H_TBL + (600 + which*100) * 56;
        for (int idx = tid; idx < 5600; idx += 256) {
            const int r = idx / 56, c = idx % 56;
            wsh[base + idx] = __float2half_rn((c < 50) ? E[r*50 + c] : 0.0f);
        }
    } else if (bid < 177) {
        const int v = (bid - 152)*4 + (tid >> 6);
        const int t = tid & 63;
        if (t < 50) {
            float acc = b_bin[t];
#pragma unroll
            for (int e = 0; e < 50; ++e)
                acc += oe[v*50 + e] * W_bin[(50 + e)*50 + t];
            wsh[H_TO + (v*50 + t)*2]     = __float2half_rn(acc);
            wsh[H_TO + (v*50 + t)*2 + 1] = __float2half_rn(oe[v*50 + t]);
        }
    } else if (bid == 177) {
        const int n = tid & 63, kc = tid >> 6;
        for (int k = kc*29; k < kc*29 + 29; ++k) {
            float val = 0.0f;
            if (n < 50) {
                if (k < 50)       val = W_bin[k*50 + n];
                else if (k < 100) val = W_bin[(100 + k - 50)*50 + n];
            }
            wsh[H_WC + n*116 + k] = __float2half_rn(val);
        }
    } else if (bid == 178) {
        const int n = tid & 63;
        const int half = tid >> 7;
        const int kc = (tid >> 6) & 1;
        const float* W = half ? W_univ : W_un;
        const int base = half ? H_WV : H_WU;
        for (int k = kc*34; k < kc*34 + 34; ++k) {
            float val = (n < 50 && k < 50) ? W[k*50 + n] : 0.0f;
            wsh[base + n*68 + k] = __float2half_rn(val);
        }
    } else if (bid == 179) {
        for (int idx = tid; idx < 10880; idx += 256) {
            const int n = idx % 160, k = idx / 160;
            float val = (n < ODIM && k < 50) ? W_fin[k*ODIM + n] : 0.0f;
            wsh[H_WF + n*68 + k] = __float2half_rn(val);
        }
    } else {                                // bid == 180: logits fp32 + watt half2
        for (int g = tid; g < 300; g += 256) {
            const int which = g / VOCABSZ, v = g % VOCABSZ;
            const float* E = (which == 0) ? pe : ((which == 1) ? ve : oe);
            float acc = b_att[0];
#pragma unroll
            for (int e = 0; e < 50; ++e)
                acc += E[v*50 + e] * W_att[e];
            ws[F_LG + g] = acc;
        }
        if (tid < 28) {
            const float x = (2*tid < 50)   ? W_att[2*tid]   : 0.0f;
            const float y = (2*tid+1 < 50) ? W_att[2*tid+1] : 0.0f;
            ((__half2*)(wsh + H_WATT))[tid] = __floats2half2_rn(x, y);
        }
    }
}

// ---------------------------------------------------------------------------
// Build one predicate node — packed fp16 from GLOBAL tables (r15 proven)
// ---------------------------------------------------------------------------
__device__ __forceinline__ float build_node(
    int p, const int* __restrict__ v, __half2 e02, const __half2* __restrict__ ek2,
    __half2 invs, const uint4* __restrict__ tq, const __half2* __restrict__ wattl,
    __half2* __restrict__ h2out)
{
    const __half2 z2 = __floats2half2_rn(0.0f, 0.0f);
    __half2 lacc = z2;
#pragma unroll
    for (int g = 0; g < 7; ++g) {
        uint4 ul = tq[p*7 + g];
        uint4 up = tq[(600 + p)*7 + g];
        __half2 lin[4], num[4];
#pragma unroll
        for (int k = 0; k < 4; ++k) {
            lin[k] = ((const __half2*)&ul)[k];
            num[k] = __hmul2(e02, ((const __half2*)&up)[k]);
        }
#pragma unroll
        for (int s = 0; s < 5; ++s) {
            uint4 ua = tq[((s+1)*VOCABSZ + v[s])*7 + g];
            uint4 uv = tq[(700 + v[s])*7 + g];
#pragma unroll
            for (int k = 0; k < 4; ++k) {
                lin[k] = __hadd2(lin[k], ((const __half2*)&ua)[k]);
                num[k] = __hfma2(ek2[s], ((const __half2*)&uv)[k], num[k]);
            }
        }
#pragma unroll
        for (int k = 0; k < 4; ++k) {
            const __half2 h = __hfma2(num[k], invs, relu2(lin[k]));
            h2out[g*4 + k] = h;
            lacc = __hfma2(h, wattl[g*4 + k], lacc);
        }
    }
    return __low2float(lacc) + __high2float(lacc);
}

// ---------------------------------------------------------------------------
// Fused kernel v3.2: 256-thr (4-wave) blocks, zero barriers, each wave fully
// self-contained on a private 4.7KB LDS slab (r16 structure — 42% occupancy
// proven). LDS padded to 36864B so the allocator's LDS-occupancy model caps
// at 4 WGs/CU = 4 waves/EU -> 128-VGPR budget -> no h-state spills (r15's
// clean allocation, r16/17's residency).
// ---------------------------------------------------------------------------
__global__ __launch_bounds__(256)
void fused_kernel(
    const float* __restrict__ b_att,
    const float* __restrict__ b_un, const float* __restrict__ b_univ,
    const float* __restrict__ b_fin,
    const int* __restrict__ pred_ids, const int* __restrict__ var_ids,
    const int* __restrict__ op_ids,
    const float* __restrict__ ws, float* __restrict__ out)
{
    __shared__ __align__(16) char ldsraw[LDS_BYTES];
    const __half* wsh = (const __half*)ws;
    const int tid = threadIdx.x;
    const int w = tid >> 6, l = tid & 63;
    const int lr = l & 15, q = l >> 4;
    const int jwb = blockIdx.x*256 + w*64;      // this wave's node base
    const int j = jwb + l;

    char* wbase = ldsraw + w*LB_WAVE;
    char* slab  = wbase;                        // [16][232B]
    int*   opw = (int*)(wbase + 3712);
    float* w0w = (float*)(wbase + 3968);
    float* w2w = (float*)(wbase + 4224);
    float* w1w = (float*)(wbase + 4480);

    const float* lgf = ws + F_LG;               // global, L2-hot
    const float batt = b_att[0];

    // ---- P1: packed-fp16 gather-build from global tables ----
    int vA[5], vB[5];
    const int pA = pred_ids[2*j], pB = pred_ids[2*j+1];
#pragma unroll
    for (int s = 0; s < 5; ++s) { vA[s] = var_ids[(2*j)*5 + s]; vB[s] = var_ids[(2*j+1)*5 + s]; }
    const int op = op_ids[j];

    float ekA[5], ekB[5];
    const float e0A = __expf(lgf[pA]);
    const float e0B = __expf(lgf[pB]);
    float denA = e0A, denB = e0B;
#pragma unroll
    for (int s = 0; s < 5; ++s) {
        ekA[s] = __expf(lgf[VOCABSZ + vA[s]]); denA += ekA[s];
        ekB[s] = __expf(lgf[VOCABSZ + vB[s]]); denB += ekB[s];
    }
    const float invA = 1.0f / denA, invB = 1.0f / denB;

    __half2 ek2A[5], ek2B[5];
#pragma unroll
    for (int s = 0; s < 5; ++s) {
        ek2A[s] = __float2half2_rn(ekA[s]);
        ek2B[s] = __float2half2_rn(ekB[s]);
    }

    const uint4* tq = (const uint4*)wsh;
    const __half2* wattg = (const __half2*)(wsh + H_WATT);   // lane-uniform

    __half2 hA2[28], hB2[28];
    const float w0 = __expf(batt + build_node(pA, vA, __float2half2_rn(e0A), ek2A,
                                              __float2half2_rn(invA), tq, wattg, hA2));
    const float w2 = __expf(batt + build_node(pB, vB, __float2half2_rn(e0B), ek2B,
                                              __float2half2_rn(invB), tq, wattg, hB2));
    const float w1 = __expf(lgf[2*VOCABSZ + op]);
    const float inv2 = 1.0f / (w0 + w1 + w2);

    // publish per-node scalars (own wave only -> wave-synchronous, no barrier)
    opw[l] = op;
    w0w[l] = w0*inv2; w2w[l] = w2*inv2; w1w[l] = w1*inv2;

    const __half2* TOg = (const __half2*)(wsh + H_TO);
    const char* Wcg = (const char*)(wsh + H_WC);    // 232B rows, global L2
    const char* Wug = (const char*)(wsh + H_WU);    // 136B rows
    const char* Wvg = (const char*)(wsh + H_WV);
    const char* Wfg = (const char*)(wsh + H_WF);

    for (int c = 0; c < 4; ++c) {
        // ---- owner lanes write chunk H rows [hA|hB|zeros] ----
        if ((l >> 4) == c) {
            uint* dst = (uint*)(slab + (l & 15)*232);
#pragma unroll
            for (int i = 0; i < 25; ++i) { uint u; __builtin_memcpy(&u, &hA2[i], 4); dst[i] = u; }
#pragma unroll
            for (int i = 0; i < 25; ++i) { uint u; __builtin_memcpy(&u, &hB2[i], 4); dst[25+i] = u; }
#pragma unroll
            for (int i = 50; i < 58; ++i) dst[i] = 0u;
        }

        // ---- GEMM1: lin2[16x64] = H[16x116(100)] @ Wcat (B from global) ----
        f32x4 C1[4];
#pragma unroll
        for (int nt = 0; nt < 4; ++nt) C1[nt] = (f32x4){0.f, 0.f, 0.f, 0.f};
#pragma unroll
        for (int kk = 0; kk < 7; ++kk) {
            f16x4 a = *(const f16x4*)(slab + lr*232 + kk*32 + q*8);
#pragma unroll
            for (int nt = 0; nt < 4; ++nt) {
                f16x4 b = *(const f16x4*)(Wcg + (nt*16 + lr)*232 + kk*32 + q*8);
                C1[nt] = __builtin_amdgcn_mfma_f32_16x16x16f16(a, b, C1[nt], 0, 0, 0);
            }
        }
        // epilogue: h_bin = relu(lin2 + Tb[op]) + w0i*hA + w2i*hB + w1i*oe[op]
        {
            const __half* sh = (const __half*)slab;
            const int cb = c*16;
#pragma unroll
            for (int nt = 0; nt < 4; ++nt) {
                const int d = nt*16 + lr;
#pragma unroll
                for (int r = 0; r < 4; ++r) {
                    float v = 0.0f;
                    if (d < LDIM) {
                        const int nw = cb + q*4 + r;
                        const int opn = opw[nw];
                        const float2 to = __half22float2(TOg[opn*LDIM + d]);   // {Tb, oe}
                        const float hAv = __half2float(sh[(q*4 + r)*116 + d]);
                        const float hBv = __half2float(sh[(q*4 + r)*116 + 50 + d]);
                        v = fmaxf(C1[nt][r] + to.x, 0.0f)
                          + w0w[nw]*hAv + w2w[nw]*hBv + w1w[nw]*to.y;
                    }
                    C1[nt][r] = v;
                }
            }
            __half* shw = (__half*)slab;
#pragma unroll
            for (int nt = 0; nt < 4; ++nt)
#pragma unroll
                for (int r = 0; r < 4; ++r)
                    shw[(q*4 + r)*116 + nt*16 + lr] = __float2half(C1[nt][r]);
        }

        // ---- GEMM2: h_un = relu(h_bin @ W_un + b_un) ----
        {
            f32x4 C2[4];
#pragma unroll
            for (int nt = 0; nt < 4; ++nt) C2[nt] = (f32x4){0.f, 0.f, 0.f, 0.f};
#pragma unroll
            for (int kk = 0; kk < 4; ++kk) {
                f16x4 a = *(const f16x4*)(slab + lr*232 + kk*32 + q*8);
#pragma unroll
                for (int nt = 0; nt < 4; ++nt) {
                    f16x4 b = *(const f16x4*)(Wug + (nt*16 + lr)*136 + kk*32 + q*8);
                    C2[nt] = __builtin_amdgcn_mfma_f32_16x16x16f16(a, b, C2[nt], 0, 0, 0);
                }
            }
            __half* shw = (__half*)slab;
#pragma unroll
            for (int nt = 0; nt < 4; ++nt) {
                const int d = nt*16 + lr;
                const float bu = (d < LDIM) ? b_un[d] : 0.0f;
#pragma unroll
                for (int r = 0; r < 4; ++r) {
                    const float v = (d < LDIM) ? fmaxf(C2[nt][r] + bu, 0.0f) : 0.0f;
                    shw[(q*4 + r)*116 + d] = __float2half(v);
                }
            }
        }

        // ---- GEMM3: h_q = relu(h_un @ W_univ + b_univ) ----
        {
            f32x4 C3[4];
#pragma unroll
            for (int nt = 0; nt < 4; ++nt) C3[nt] = (f32x4){0.f, 0.f, 0.f, 0.f};
#pragma unroll
            for (int kk = 0; kk < 4; ++kk) {
                f16x4 a = *(const f16x4*)(slab + lr*232 + kk*32 + q*8);
#pragma unroll
                for (int nt = 0; nt < 4; ++nt) {
                    f16x4 b = *(const f16x4*)(Wvg + (nt*16 + lr)*136 + kk*32 + q*8);
                    C3[nt] = __builtin_amdgcn_mfma_f32_16x16x16f16(a, b, C3[nt], 0, 0, 0);
                }
            }
            __half* shw = (__half*)slab;
#pragma unroll
            for (int nt = 0; nt < 4; ++nt) {
                const int d = nt*16 + lr;
                const float bv = (d < LDIM) ? b_univ[d] : 0.0f;
#pragma unroll
                for (int r = 0; r < 4; ++r) {
                    const float v = (d < LDIM) ? fmaxf(C3[nt][r] + bv, 0.0f) : 0.0f;
                    shw[(q*4 + r)*116 + d] = __float2half(v);
                }
            }
        }

        // ---- GEMM4: out = h_q @ W_fin + b_fin (B from global L2) ----
        {
            float* gb = out + (size_t)(jwb + c*16) * ODIM;
            for (int nt = 0; nt < 10; ++nt) {
                f16x4 bf[4];
#pragma unroll
                for (int kk = 0; kk < 4; ++kk)
                    bf[kk] = *(const f16x4*)(Wfg + (nt*16 + lr)*136 + kk*32 + q*8);
                f32x4 c4 = (f32x4){0.f, 0.f, 0.f, 0.f};
#pragma unroll
                for (int kk = 0; kk < 4; ++kk) {
                    f16x4 a = *(const f16x4*)(slab + lr*232 + kk*32 + q*8);
                    c4 = __builtin_amdgcn_mfma_f32_16x16x16f16(a, bf[kk], c4, 0, 0, 0);
                }
                const int o = nt*16 + lr;
                const float bv = (o < ODIM) ? b_fin[o] : 0.0f;
#pragma unroll
                for (int r = 0; r < 4; ++r)
                    *(float*)(slab + (q*4 + r)*232 + 128 + lr*4) = c4[r] + bv;
#pragma unroll
                for (int it = 0; it < 4; ++it) {
                    const int row = it*4 + q;
                    if (o < ODIM)
                        gb[row*ODIM + nt*16 + lr] =
                            *(const float*)(slab + row*232 + 128 + lr*4);
                }
            }
        }
    }
}

// ---------------------------------------------------------------------------
extern "C" void kernel_launch(void* const* d_in, const int* in_sizes, int n_in,
                              void* d_out, int out_size, void* d_ws, size_t ws_size,
                              hipStream_t stream) {
    const float* pe     = (const float*)d_in[0];
    const float* ve     = (const float*)d_in[1];
    const float* oe     = (const float*)d_in[2];
    const float* W_pred = (const float*)d_in[3];
    const float* b_pred = (const float*)d_in[4];
    const float* W_bin  = (const float*)d_in[5];
    const float* b_bin  = (const float*)d_in[6];
    const float* W_un   = (const float*)d_in[7];
    const float* b_un   = (const float*)d_in[8];
    const float* W_univ = (const float*)d_in[9];
    const float* b_univ = (const float*)d_in[10];
    const float* W_att  = (const float*)d_in[11];
    const float* b_att  = (const float*)d_in[12];
    const float* W_fin  = (const float*)d_in[13];
    const float* b_fin  = (const float*)d_in[14];
    const int* pred_ids = (const int*)d_in[15];
    const int* var_ids  = (const int*)d_in[16];
    const int* op_ids   = (const int*)d_in[17];
    float* out = (float*)d_out;
    float* ws  = (float*)d_ws;

    precompute_kernel<<<181, 256, 0, stream>>>(pe, ve, oe, W_pred, b_pred,
                                               W_bin, b_bin, W_un, W_univ, W_fin,
                                               W_att, b_att, ws);
    fused_kernel<<<MBIN/256, 256, 0, stream>>>(b_att, b_un, b_univ, b_fin,
                                               pred_ids, var_ids, op_ids, ws, out);
}